// Round 9
// baseline (12889.323 us; speedup 1.0000x reference)
//
#include <hip/hip_runtime.h>
#include <hip/hip_bf16.h>
#include <cstdint>
#include <cstddef>

typedef unsigned short u16;
typedef __attribute__((ext_vector_type(4))) float f32x4;
typedef __attribute__((ext_vector_type(8))) short short8;

#define B_SZ 256
#define T_SZ 256
#define IN_SZ 64
#define H_SZ 512
#define G3 1536
#define NG 16            // 16 batch groups of 16 rows
#define H0_SLOTS 32
#define GX_SLOTS 8

__device__ __forceinline__ u16 f2bf(float f) {
  union { float f; unsigned int i; } v; v.f = f;
  unsigned int x = v.i;
  unsigned int r = (x + 0x7fffu + ((x >> 16) & 1u)) >> 16;  // RNE
  return (u16)r;
}
__device__ __forceinline__ float sigmoidf_(float x) { return 1.0f / (1.0f + __expf(-x)); }
__device__ __forceinline__ float tanhf_(float x) {
  float e = __expf(-2.0f * x); return (1.0f - e) / (1.0f + e);
}

// PROVEN primitives only (R4/R5): relaxed agent-scope flag poll/publish +
// L1-only invalidate before reading same-XCD L2 data.
__device__ __forceinline__ void poll_ge(int* p, int v) {
  int cap = 0;
  while (__hip_atomic_load(p, __ATOMIC_RELAXED, __HIP_MEMORY_SCOPE_AGENT) < v) {
    __builtin_amdgcn_s_sleep(1);
    if (++cap > 200000) break;   // hang breaker; never hit in normal runs
  }
  __builtin_amdgcn_sched_barrier(0);
  asm volatile("buffer_inv sc0" ::: "memory");   // L1 invalidate (R4/5-proven)
}
__device__ __forceinline__ void st_flag(int* p, int v) {
  __hip_atomic_store(p, v, __ATOMIC_RELAXED, __HIP_MEMORY_SCOPE_AGENT);
}
__device__ __forceinline__ void add_flag(int* p) {
  __hip_atomic_fetch_add(p, 1, __ATOMIC_RELAXED, __HIP_MEMORY_SCOPE_AGENT);
}

// ---------------- weight-norm + bf16 cast: one wave per row ----------------
__global__ __launch_bounds__(256)
void norm_cast_kernel(const float* __restrict__ v, const float* __restrict__ g,
                      u16* __restrict__ out, int cols) {
  int row = blockIdx.x * 4 + (threadIdx.x >> 6);
  int lane = threadIdx.x & 63;
  const float* vr = v + (size_t)row * cols;
  float s = 0.f;
  for (int c = lane; c < cols; c += 64) { float t = vr[c]; s += t * t; }
  for (int o = 32; o; o >>= 1) s += __shfl_xor(s, o);
  float scale = g[row] / sqrtf(s);
  for (int c = lane; c < cols; c += 64) out[(size_t)row * cols + c] = f2bf(vr[c] * scale);
}

__global__ __launch_bounds__(256)
void castx_kernel(const float* __restrict__ x, u16* __restrict__ xb) {
  int i = blockIdx.x * 256 + threadIdx.x;
  float4 v = ((const float4*)x)[i];
  ushort4 o;
  o.x = f2bf(v.x); o.y = f2bf(v.y); o.z = f2bf(v.z); o.w = f2bf(v.w);
  ((ushort4*)xb)[i] = o;
}

// ---------------- fused pipeline: intra-block recurrence + gx1 army ---------
// 256 blocks x 1024 thr. Claim role on own XCD (pigeonhole 32/XCD, r>=16 exit).
// Per XCD: 2 groups x {1 L0 blk, 1 L1 blk, 6 army blks} = 16 active blocks.
// L0/L1: 16 waves; wave w owns units [w*32,+32): Whh frags in 384 VGPRs;
// h(t) exchanged via 32KB LDS dbuf (XOR-swizzled); ONE barrier per step.
// Army: 4 waves (tid<256); Wih1 slice (256 gates) in 256 VGPRs; computes
// gx1 = Wih1 . h0(t) -> f32 ring. All cross-block edges forward-pipelined.
__global__ __launch_bounds__(1024)
void pipeline_kernel(const u16* __restrict__ whh0c, const u16* __restrict__ wih0c,
                     const u16* __restrict__ whh1c, const u16* __restrict__ wih1c,
                     const float* __restrict__ bih0, const float* __restrict__ bhh0,
                     const float* __restrict__ bih1, const float* __restrict__ bhh1,
                     const u16* __restrict__ xb, u16* __restrict__ h0ring,
                     float* __restrict__ gx1ring, float* __restrict__ h1fin,
                     int* __restrict__ h0flag, int* __restrict__ armycnt,
                     int* __restrict__ l1flag, int* __restrict__ claim) {
  __shared__ char hl[32768];    // h dbuf: 2 x [16 rows][512 units] bf16, swizzled
  __shared__ int role_sh;

  const int tid = threadIdx.x;
  if (tid == 0) {
    int xcd;
    asm volatile("s_getreg_b32 %0, hwreg(HW_REG_XCC_ID)" : "=s"(xcd));
    xcd &= 7;
    role_sh = (xcd << 5) + atomicAdd(&claim[xcd], 1);
  }
  __syncthreads();
  const int xcd = role_sh >> 5;
  const int r = role_sh & 31;
  if (r >= 16) return;                 // spare block: free the CU

  const int lane = tid & 63;
  const int l15 = lane & 15;
  const int q = lane >> 4;

  if (r >= 4) {
    // ---------------- ARMY: gx1(t) = Wih1 . h0(t) ----------------
    if (tid >= 256) return;            // 4 waves
    const int idx = r - 4;             // 0..11
    const int g = xcd * 2 + (idx & 1);
    const int sl = idx >> 1;           // 0..5 -> gate rows [sl*256,+256)
    const int w4 = tid >> 6;
    short8 wf[4][16];
    #pragma unroll
    for (int nt = 0; nt < 4; ++nt)
      #pragma unroll
      for (int kk = 0; kk < 16; ++kk)
        wf[nt][kk] = *(const short8*)(wih1c
            + (size_t)(sl * 256 + w4 * 64 + nt * 16 + l15) * 512 + kk * 32 + q * 8);
    for (int t = 0; t < T_SZ; ++t) {
      poll_ge(&h0flag[g], t + 1);                 // h0(t) published
      if (t >= GX_SLOTS) poll_ge(&l1flag[g], t - (GX_SLOTS - 1));  // WAR gx slot
      f32x4 a4[4] = {};
      const u16* hp = h0ring + ((size_t)(t & (H0_SLOTS - 1)) * 256 + g * 16 + l15) * 512;
      #pragma unroll
      for (int kk = 0; kk < 16; ++kk) {
        short8 a = *(const short8*)(hp + kk * 32 + q * 8);
        #pragma unroll
        for (int nt = 0; nt < 4; ++nt)
          a4[nt] = __builtin_amdgcn_mfma_f32_16x16x32_bf16(a, wf[nt][kk], a4[nt], 0, 0, 0);
      }
      float* gxp = gx1ring + ((size_t)(t & (GX_SLOTS - 1)) * NG + g) * (16 * G3);
      #pragma unroll
      for (int nt = 0; nt < 4; ++nt)
        #pragma unroll
        for (int r2 = 0; r2 < 4; ++r2)
          gxp[(size_t)(q * 4 + r2) * G3 + sl * 256 + w4 * 64 + nt * 16 + l15] = a4[nt][r2];
      asm volatile("s_waitcnt vmcnt(0)" ::: "memory");
      __syncthreads();
      if (tid == 0) add_flag(&armycnt[g]);        // reaches 6*(t+1)
    }
    return;
  }

  // ---------------- RECURRENCE (L0: r<2, L1: r in {2,3}) ----------------
  const int L = (r >= 2);
  const int g = xcd * 2 + (L ? r - 2 : r);
  const int w = tid >> 6;              // wave 0..15 -> units [w*32,+32)

  const u16* whhc = L ? whh1c : whh0c;
  short8 whf[3][2][16];                // 384 VGPR: the wave's Whh slice
  #pragma unroll
  for (int gi = 0; gi < 3; ++gi)
    #pragma unroll
    for (int nt = 0; nt < 2; ++nt)
      #pragma unroll
      for (int kk = 0; kk < 16; ++kk)
        whf[gi][nt][kk] = *(const short8*)(whhc
            + (size_t)(gi * 512 + w * 32 + nt * 16 + l15) * 512 + kk * 32 + q * 8);

  const float* bi = L ? bih1 : bih0;
  const float* bh = L ? bhh1 : bhh0;
  float bs_r[2], bs_z[2], bn_i[2], bn_h[2];
  #pragma unroll
  for (int nt = 0; nt < 2; ++nt) {
    int u = w * 32 + nt * 16 + l15;
    bs_r[nt] = bi[u] + bh[u];
    bs_z[nt] = bi[512 + u] + bh[512 + u];
    bn_i[nt] = bi[1024 + u];
    bn_h[nt] = bh[1024 + u];
  }
  float h_old[2][4] = {};
  __syncthreads();                     // hl not yet used; aligns wave start

  if (L == 0) {
    for (int t = 0; t < T_SZ; ++t) {
      if (t >= H0_SLOTS) poll_ge(&armycnt[g], 6 * (t - (H0_SLOTS - 1)));  // WAR
      f32x4 acc[4][2] = {};            // [r, z, xn, hn][nt]
      const u16* xrow = xb + ((size_t)(g * 16 + l15) * T_SZ + t) * 64;
      #pragma unroll
      for (int kk2 = 0; kk2 < 2; ++kk2) {
        short8 ax = *(const short8*)(xrow + kk2 * 32 + q * 8);
        #pragma unroll
        for (int gi = 0; gi < 3; ++gi)
          #pragma unroll
          for (int nt = 0; nt < 2; ++nt) {
            short8 wx = *(const short8*)(wih0c
                + (size_t)(gi * 512 + w * 32 + nt * 16 + l15) * 64 + kk2 * 32 + q * 8);
            int ai = (gi == 2) ? 2 : gi;
            acc[ai][nt] = __builtin_amdgcn_mfma_f32_16x16x32_bf16(ax, wx, acc[ai][nt], 0, 0, 0);
          }
      }
      if (t > 0) {
        const int rb = (t - 1) & 1;
        #pragma unroll
        for (int kk = 0; kk < 16; ++kk) {
          short8 a = *(const short8*)(hl + rb * 16384 + l15 * 1024
                                      + (((kk * 32 + q * 8) * 2) ^ ((l15 & 7) << 4)));
          #pragma unroll
          for (int gi = 0; gi < 3; ++gi)
            #pragma unroll
            for (int nt = 0; nt < 2; ++nt) {
              int ai = (gi == 2) ? 3 : gi;
              acc[ai][nt] = __builtin_amdgcn_mfma_f32_16x16x32_bf16(a, whf[gi][nt][kk], acc[ai][nt], 0, 0, 0);
            }
        }
      }
      u16* hgl = h0ring + ((size_t)(t & (H0_SLOTS - 1)) * 256 + g * 16) * 512;
      #pragma unroll
      for (int nt = 0; nt < 2; ++nt) {
        int unit = w * 32 + nt * 16 + l15;
        #pragma unroll
        for (int r2 = 0; r2 < 4; ++r2) {
          int rw = q * 4 + r2;
          float rr = sigmoidf_(acc[0][nt][r2] + bs_r[nt]);
          float zz = sigmoidf_(acc[1][nt][r2] + bs_z[nt]);
          float nn = tanhf_(acc[2][nt][r2] + bn_i[nt] + rr * (acc[3][nt][r2] + bn_h[nt]));
          float hv = (1.0f - zz) * nn + zz * h_old[nt][r2];
          h_old[nt][r2] = hv;
          u16 hb = f2bf(hv);
          *(u16*)(hl + (t & 1) * 16384 + rw * 1024 + ((unit * 2) ^ ((rw & 7) << 4))) = hb;
          hgl[(size_t)rw * 512 + unit] = hb;
        }
      }
      asm volatile("s_waitcnt vmcnt(0)" ::: "memory");  // h0 publish in L2
      __syncthreads();
      if (tid == 0) st_flag(&h0flag[g], t + 1);
    }
  } else {
    for (int t = 0; t < T_SZ; ++t) {
      poll_ge(&armycnt[g], 6 * (t + 1));          // gx1(t) ready
      f32x4 acc[3][2] = {};            // [r, z, hn][nt]
      if (t > 0) {
        const int rb = (t - 1) & 1;
        #pragma unroll
        for (int kk = 0; kk < 16; ++kk) {
          short8 a = *(const short8*)(hl + rb * 16384 + l15 * 1024
                                      + (((kk * 32 + q * 8) * 2) ^ ((l15 & 7) << 4)));
          #pragma unroll
          for (int gi = 0; gi < 3; ++gi)
            #pragma unroll
            for (int nt = 0; nt < 2; ++nt)
              acc[gi][nt] = __builtin_amdgcn_mfma_f32_16x16x32_bf16(a, whf[gi][nt][kk], acc[gi][nt], 0, 0, 0);
        }
      }
      const float* gxp = gx1ring + ((size_t)(t & (GX_SLOTS - 1)) * NG + g) * (16 * G3);
      #pragma unroll
      for (int nt = 0; nt < 2; ++nt) {
        int unit = w * 32 + nt * 16 + l15;
        #pragma unroll
        for (int r2 = 0; r2 < 4; ++r2) {
          int rw = q * 4 + r2;
          float xr = gxp[(size_t)rw * G3 + unit];
          float xz = gxp[(size_t)rw * G3 + 512 + unit];
          float xn = gxp[(size_t)rw * G3 + 1024 + unit];
          float rr = sigmoidf_(xr + acc[0][nt][r2] + bs_r[nt]);
          float zz = sigmoidf_(xz + acc[1][nt][r2] + bs_z[nt]);
          float nn = tanhf_(xn + bn_i[nt] + rr * (acc[2][nt][r2] + bn_h[nt]));
          float hv = (1.0f - zz) * nn + zz * h_old[nt][r2];
          h_old[nt][r2] = hv;
          *(u16*)(hl + (t & 1) * 16384 + rw * 1024 + ((unit * 2) ^ ((rw & 7) << 4))) = f2bf(hv);
          if (t == T_SZ - 1) h1fin[((size_t)g * 16 + rw) * 512 + unit] = hv;
        }
      }
      __syncthreads();
      if (tid == 0) st_flag(&l1flag[g], t + 1);   // gx slot t&7 consumed
    }
  }
}

// ---------------- final FC: out[b] = h1[b,:] . w_fc + b_fc ------------------
__global__ __launch_bounds__(256)
void fc_kernel(const float* __restrict__ h, const float* __restrict__ w,
               const float* __restrict__ bfc, float* __restrict__ out) {
  int b = blockIdx.x; int tid = threadIdx.x;
  float s = h[(size_t)b * 512 + tid] * w[tid] + h[(size_t)b * 512 + tid + 256] * w[tid + 256];
  for (int o = 32; o; o >>= 1) s += __shfl_xor(s, o);
  __shared__ float ws4[4];
  if ((tid & 63) == 0) ws4[tid >> 6] = s;
  __syncthreads();
  if (tid == 0) out[b] = ws4[0] + ws4[1] + ws4[2] + ws4[3] + bfc[0];
}

extern "C" void kernel_launch(void* const* d_in, const int* in_sizes, int n_in,
                              void* d_out, int out_size, void* d_ws, size_t ws_size,
                              hipStream_t stream) {
  const float* x     = (const float*)d_in[0];
  const float* v_ih0 = (const float*)d_in[1];
  const float* g_ih0 = (const float*)d_in[2];
  const float* b_ih0 = (const float*)d_in[3];
  const float* v_hh0 = (const float*)d_in[4];
  const float* g_hh0 = (const float*)d_in[5];
  const float* b_hh0 = (const float*)d_in[6];
  const float* v_ih1 = (const float*)d_in[7];
  const float* g_ih1 = (const float*)d_in[8];
  const float* b_ih1 = (const float*)d_in[9];
  const float* v_hh1 = (const float*)d_in[10];
  const float* g_hh1 = (const float*)d_in[11];
  const float* b_hh1 = (const float*)d_in[12];
  const float* w_fc  = (const float*)d_in[13];
  const float* b_fc  = (const float*)d_in[14];
  float* out = (float*)d_out;

  char* w = (char*)d_ws;
  size_t off = 0;
  auto alloc = [&](size_t bytes) -> char* {
    char* p = w + off; off += (bytes + 255) & ~(size_t)255; return p;
  };
  int*   flags   = (int*)alloc(256);   // h0flag[16] armycnt[16] l1flag[16] claim[8]
  float* h1fin   = (float*)alloc((size_t)256 * 512 * 4);
  u16*   h0ring  = (u16*)alloc((size_t)H0_SLOTS * 256 * 512 * 2);       // 8MB
  float* gx1ring = (float*)alloc((size_t)GX_SLOTS * NG * 16 * G3 * 4);  // 12.6MB
  u16*   xb      = (u16*)alloc((size_t)B_SZ * T_SZ * IN_SZ * 2);
  u16*   wih0c   = (u16*)alloc((size_t)G3 * IN_SZ * 2);
  u16*   whh0c   = (u16*)alloc((size_t)G3 * H_SZ * 2);
  u16*   wih1c   = (u16*)alloc((size_t)G3 * H_SZ * 2);
  u16*   whh1c   = (u16*)alloc((size_t)G3 * H_SZ * 2);
  if (off > ws_size) return;  // ~26MB; evidenced ws >= 140MB

  hipMemsetAsync(flags, 0, 256, stream);
  norm_cast_kernel<<<384, 256, 0, stream>>>(v_ih0, g_ih0, wih0c, IN_SZ);
  norm_cast_kernel<<<384, 256, 0, stream>>>(v_hh0, g_hh0, whh0c, H_SZ);
  norm_cast_kernel<<<384, 256, 0, stream>>>(v_ih1, g_ih1, wih1c, H_SZ);
  norm_cast_kernel<<<384, 256, 0, stream>>>(v_hh1, g_hh1, whh1c, H_SZ);
  castx_kernel<<<4096, 256, 0, stream>>>(x, xb);

  pipeline_kernel<<<256, 1024, 0, stream>>>(whh0c, wih0c, whh1c, wih1c,
                                            b_ih0, b_hh0, b_ih1, b_hh1,
                                            xb, h0ring, gx1ring, h1fin,
                                            flags, flags + 16, flags + 32, flags + 48);
  fc_kernel<<<256, 256, 0, stream>>>(h1fin, w_fc, b_fc, out);
}

// Round 10
// 3740.029 us; speedup vs baseline: 3.4463x; 3.4463x over previous
//
#include <hip/hip_runtime.h>
#include <hip/hip_bf16.h>
#include <cstdint>
#include <cstddef>

typedef unsigned short u16;
typedef __attribute__((ext_vector_type(4))) float f32x4;
typedef __attribute__((ext_vector_type(8))) short short8;

#define B_SZ 256
#define T_SZ 256
#define IN_SZ 64
#define H_SZ 512
#define G3 1536
#define BH (256 * 512)   // elements per h ring slot

__device__ __forceinline__ u16 f2bf(float f) {
  union { float f; unsigned int i; } v; v.f = f;
  unsigned int x = v.i;
  unsigned int r = (x + 0x7fffu + ((x >> 16) & 1u)) >> 16;  // RNE
  return (u16)r;
}
__device__ __forceinline__ float sigmoidf_(float x) { return 1.0f / (1.0f + __expf(-x)); }
__device__ __forceinline__ float tanhf_(float x) {
  float e = __expf(-2.0f * x); return (1.0f - e) / (1.0f + e);
}

// ---- flag primitives: L2-level fast path + L3 (R5-proven) safety net ----
// Publish: plain store lands in the shared XCD L2 (L1 is write-through);
// the sc1 atomic store is the R4/R5-proven L3 path. Same monotone value ->
// any interleaving is safe.
__device__ __forceinline__ void st_flag_dual(int* p, int v) {
  asm volatile("global_store_dword %0, %1, off" :: "v"(p), "v"(v) : "memory");
  __hip_atomic_store(p, v, __ATOMIC_RELAXED, __HIP_MEMORY_SCOPE_AGENT);
}
// Poll fast path: L1-inv + plain load + waitcnt fused in ONE asm (rule #18:
// the output reg is unusable before the wait). Reads the shared XCD L2.
__device__ __forceinline__ int ld_flag_fast(const int* p) {
  int v;
  asm volatile("buffer_inv sc0\n\t"
               "global_load_dword %0, %1, off\n\t"
               "s_waitcnt vmcnt(0)"
               : "=v"(v) : "v"(p) : "memory");
  return v;
}
// Wave-wide spin: lane i polls flag i (64 flags/group/layer). Every 16th
// iteration also reads via the sc1 atomic (R5-proven) -> correctness does not
// depend on the fast path at all; worst case == R5 behavior at 1/16 poll rate.
__device__ __forceinline__ void wave_spin(int* f, int v) {
  int* p = f + (threadIdx.x & 63);
  int cap = 0;
  while (true) {
    int x = ld_flag_fast(p);
    if (__all(x >= v)) break;
    if ((cap & 15) == 15) {
      x = __hip_atomic_load(p, __ATOMIC_RELAXED, __HIP_MEMORY_SCOPE_AGENT);
      if (__all(x >= v)) break;
    }
    __builtin_amdgcn_s_sleep(1);
    if (++cap > 200000) break;   // hang breaker; never hit in normal runs
  }
  __builtin_amdgcn_sched_barrier(0);   // nothing hoists above the detect
  asm volatile("" ::: "memory");
}

// ---------------- weight-norm + bf16 cast: one wave per row ----------------
__global__ __launch_bounds__(256)
void norm_cast_kernel(const float* __restrict__ v, const float* __restrict__ g,
                      u16* __restrict__ out, int cols) {
  int row = blockIdx.x * 4 + (threadIdx.x >> 6);
  int lane = threadIdx.x & 63;
  const float* vr = v + (size_t)row * cols;
  float s = 0.f;
  for (int c = lane; c < cols; c += 64) { float t = vr[c]; s += t * t; }
  for (int o = 32; o; o >>= 1) s += __shfl_xor(s, o);
  float scale = g[row] / sqrtf(s);
  for (int c = lane; c < cols; c += 64) out[(size_t)row * cols + c] = f2bf(vr[c] * scale);
}

__global__ __launch_bounds__(256)
void castx_kernel(const float* __restrict__ x, u16* __restrict__ xb) {
  int i = blockIdx.x * 256 + threadIdx.x;
  float4 v = ((const float4*)x)[i];
  ushort4 o;
  o.x = f2bf(v.x); o.y = f2bf(v.y); o.z = f2bf(v.z); o.w = f2bf(v.w);
  ((ushort4*)xb)[i] = o;
}

// ---------------- fused 2-layer persistent GRU (R5 structure) ---------------
// 256 blocks x 256 thr, 1 blk/CU (LDS 96KB). Block claims role on ITS XCD:
// group g = xcd (32 batch rows), r<16 -> L0 slice r, r>=16 -> L1 slice r-16.
// Waves are independent agents (no __syncthreads in loop); Whh fragments in
// registers; L1 keeps full Wih1 slice in LDS. Flags: dual-publish (L2+L3),
// poll fast via L2 with periodic L3 (proven) fallback.
__global__ __launch_bounds__(256, 1)
void fused_rnn_kernel(const u16* __restrict__ whh0, const u16* __restrict__ wih0,
                      const float* __restrict__ bih0p, const float* __restrict__ bhh0p,
                      const u16* __restrict__ whh1, const u16* __restrict__ wih1,
                      const float* __restrict__ bih1p, const float* __restrict__ bhh1p,
                      const u16* __restrict__ xb, u16* __restrict__ h0ring,
                      u16* __restrict__ h1ring, float* __restrict__ h1fin,
                      int* __restrict__ flags, int* __restrict__ claim) {
  __shared__ u16 Wx1[96 * 512];   // L1: full Wih1 slice, swizzled, 96KB
  __shared__ int role_sh;

  const int tid = threadIdx.x;
  if (tid == 0) {
    int xcd;
    asm volatile("s_getreg_b32 %0, hwreg(HW_REG_XCC_ID)" : "=s"(xcd));
    xcd &= 7;
    int r = atomicAdd(&claim[xcd], 1);          // device-scope, once per block
    role_sh = xcd * 64 + r;
  }
  __syncthreads();
  const int g = role_sh >> 6;        // batch group == XCD
  const int r = role_sh & 63;
  if (r >= 32) return;               // can't happen (pigeonhole 32/XCD)
  const int L = r >> 4;
  const int s = r & 15;              // hidden slice (32 units)

  const int lane = tid & 63;
  const int wv = tid >> 6;           // wave id 0..3
  const int wm = wv >> 1;            // 16-row tile
  const int wk = wv & 1;             // 16-unit half
  const int q = lane >> 4;
  const int ul = wk * 16 + (lane & 15);   // local unit 0..31
  const int gu = s * 32 + ul;
  const int arow = g * 32 + wm * 16 + (lane & 15);
  const int swz = (ul & 7) << 4;
  const int wid = s * 4 + wv;        // this wave's flag index

  // L1: stage full Wih1 slice (96 rows x 1024B) swizzled into LDS
  if (L == 1) {
    for (int idx = tid; idx < 6144; idx += 256) {
      int rr = idx >> 6, c16 = idx & 63;
      int grow = (rr >> 5) * 512 + s * 32 + (rr & 31);
      int sb = (c16 << 4) ^ ((rr & 7) << 4);
      uint4 vv = *(const uint4*)((const char*)wih1 + (size_t)grow * 1024 + sb);
      *(uint4*)((char*)Wx1 + rr * 1024 + (c16 << 4)) = vv;
    }
  }

  // Whh fragments -> registers (48 x short8)
  const u16* whhp = L ? whh1 : whh0;
  short8 whf[3][16];
  #pragma unroll
  for (int g3 = 0; g3 < 3; ++g3)
    #pragma unroll
    for (int kk = 0; kk < 16; ++kk)
      whf[g3][kk] = *(const short8*)(whhp + (size_t)(g3 * 512 + s * 32 + ul) * 512
                                     + kk * 32 + q * 8);
  // L0: Wih0 fragments -> registers (6 x short8)
  short8 wxf[3][2];
  if (L == 0) {
    #pragma unroll
    for (int g3 = 0; g3 < 3; ++g3)
      #pragma unroll
      for (int k2 = 0; k2 < 2; ++k2)
        wxf[g3][k2] = *(const short8*)(wih0 + (size_t)(g3 * 512 + s * 32 + ul) * 64
                                       + k2 * 32 + q * 8);
  }
  const float* bip = L ? bih1p : bih0p;
  const float* bhp = L ? bhh1p : bhh0p;
  const float bi_r = bip[s * 32 + ul], bi_z = bip[512 + s * 32 + ul], bi_n = bip[1024 + s * 32 + ul];
  const float bh_r = bhp[s * 32 + ul], bh_z = bhp[512 + s * 32 + ul], bh_n = bhp[1024 + s * 32 + ul];

  __syncthreads();   // LDS staging visible; last barrier before the loop

  int* h0f = flags + g * 64;         // 64 L0 wave-flags of this group
  int* h1f = flags + 512 + g * 64;   // 64 L1 wave-flags of this group
  float h_reg[4] = {0.f, 0.f, 0.f, 0.f};

  if (L == 0) {
    for (int t = 0; t < T_SZ; ++t) {
      f32x4 accr = {0.f,0.f,0.f,0.f}, accz = {0.f,0.f,0.f,0.f};
      f32x4 axn  = {0.f,0.f,0.f,0.f}, ahn  = {0.f,0.f,0.f,0.f};
      // gx0: independent of peers -> before spins
      const u16* xp = xb + ((size_t)arow * T_SZ + t) * 64;
      short8 ax0 = *(const short8*)(xp + q * 8);
      short8 ax1 = *(const short8*)(xp + 32 + q * 8);
      accr = __builtin_amdgcn_mfma_f32_16x16x32_bf16(ax0, wxf[0][0], accr, 0, 0, 0);
      accz = __builtin_amdgcn_mfma_f32_16x16x32_bf16(ax0, wxf[1][0], accz, 0, 0, 0);
      axn  = __builtin_amdgcn_mfma_f32_16x16x32_bf16(ax0, wxf[2][0], axn, 0, 0, 0);
      accr = __builtin_amdgcn_mfma_f32_16x16x32_bf16(ax1, wxf[0][1], accr, 0, 0, 0);
      accz = __builtin_amdgcn_mfma_f32_16x16x32_bf16(ax1, wxf[1][1], accz, 0, 0, 0);
      axn  = __builtin_amdgcn_mfma_f32_16x16x32_bf16(ax1, wxf[2][1], axn, 0, 0, 0);
      if (t > 0) wave_spin(h0f, t);            // peers' h0(t-1)
      if (t >= 8) wave_spin(h1f, t - 7);       // WAR guard on ring slot t&7
      asm volatile("buffer_inv sc0" ::: "memory");   // L1-only invalidate
      if (t > 0) {
        const u16* hp = h0ring + (size_t)((t - 1) & 7) * BH + (size_t)arow * 512;
        #pragma unroll
        for (int kk = 0; kk < 16; ++kk) {
          short8 a = *(const short8*)(hp + kk * 32 + q * 8);
          accr = __builtin_amdgcn_mfma_f32_16x16x32_bf16(a, whf[0][kk], accr, 0, 0, 0);
          accz = __builtin_amdgcn_mfma_f32_16x16x32_bf16(a, whf[1][kk], accz, 0, 0, 0);
          ahn  = __builtin_amdgcn_mfma_f32_16x16x32_bf16(a, whf[2][kk], ahn, 0, 0, 0);
        }
      }
      u16* dst = h0ring + (size_t)(t & 7) * BH + (size_t)(g * 32 + wm * 16) * 512 + gu;
      #pragma unroll
      for (int r2 = 0; r2 < 4; ++r2) {
        float rr = sigmoidf_(accr[r2] + bi_r + bh_r);
        float zz = sigmoidf_(accz[r2] + bi_z + bh_z);
        float nn = tanhf_(axn[r2] + bi_n + rr * (ahn[r2] + bh_n));
        float hv = (1.0f - zz) * nn + zz * h_reg[r2];
        h_reg[r2] = hv;
        dst[(size_t)(q * 4 + r2) * 512] = f2bf(hv);
      }
      asm volatile("s_waitcnt vmcnt(0)" ::: "memory");  // publish drained to L2
      if (lane == 0) st_flag_dual(&h0f[wid], t + 1);
    }
  } else {
    for (int t = 0; t < T_SZ; ++t) {
      f32x4 accr = {0.f,0.f,0.f,0.f}, accz = {0.f,0.f,0.f,0.f};
      f32x4 axn  = {0.f,0.f,0.f,0.f}, ahn  = {0.f,0.f,0.f,0.f};
      wave_spin(h0f, t + 1);                   // h0(t) ready
      asm volatile("buffer_inv sc0" ::: "memory");
      {  // gx1 = Wih1 . h0(t)  (LDS B-operands) — hides the h1-peer wait
        const u16* hp0 = h0ring + (size_t)(t & 7) * BH + (size_t)arow * 512;
        #pragma unroll
        for (int kk = 0; kk < 16; ++kk) {
          short8 a0 = *(const short8*)(hp0 + kk * 32 + q * 8);
          int bofs = (kk * 64 + q * 16) ^ swz;
          short8 br = *(const short8*)((const char*)Wx1 + (size_t)ul * 1024 + bofs);
          short8 bz = *(const short8*)((const char*)Wx1 + (size_t)(32 + ul) * 1024 + bofs);
          short8 bn = *(const short8*)((const char*)Wx1 + (size_t)(64 + ul) * 1024 + bofs);
          accr = __builtin_amdgcn_mfma_f32_16x16x32_bf16(a0, br, accr, 0, 0, 0);
          accz = __builtin_amdgcn_mfma_f32_16x16x32_bf16(a0, bz, accz, 0, 0, 0);
          axn  = __builtin_amdgcn_mfma_f32_16x16x32_bf16(a0, bn, axn, 0, 0, 0);
        }
      }
      if (t > 0) {
        wave_spin(h1f, t);                     // peers' h1(t-1)
        const u16* hp1 = h1ring + (size_t)((t - 1) & 3) * BH + (size_t)arow * 512;
        #pragma unroll
        for (int kk = 0; kk < 16; ++kk) {
          short8 a1 = *(const short8*)(hp1 + kk * 32 + q * 8);
          accr = __builtin_amdgcn_mfma_f32_16x16x32_bf16(a1, whf[0][kk], accr, 0, 0, 0);
          accz = __builtin_amdgcn_mfma_f32_16x16x32_bf16(a1, whf[1][kk], accz, 0, 0, 0);
          ahn  = __builtin_amdgcn_mfma_f32_16x16x32_bf16(a1, whf[2][kk], ahn, 0, 0, 0);
        }
      }
      u16* dst = h1ring + (size_t)(t & 3) * BH + (size_t)(g * 32 + wm * 16) * 512 + gu;
      #pragma unroll
      for (int r2 = 0; r2 < 4; ++r2) {
        float rr = sigmoidf_(accr[r2] + bi_r + bh_r);
        float zz = sigmoidf_(accz[r2] + bi_z + bh_z);
        float nn = tanhf_(axn[r2] + bi_n + rr * (ahn[r2] + bh_n));
        float hv = (1.0f - zz) * nn + zz * h_reg[r2];
        h_reg[r2] = hv;
        dst[(size_t)(q * 4 + r2) * 512] = f2bf(hv);
        if (t == T_SZ - 1)
          h1fin[(size_t)(g * 32 + wm * 16 + q * 4 + r2) * 512 + gu] = hv;
      }
      asm volatile("s_waitcnt vmcnt(0)" ::: "memory");
      if (lane == 0) st_flag_dual(&h1f[wid], t + 1);
    }
  }
}

// ---------------- final FC: out[b] = h1[b,:] . w_fc + b_fc ------------------
__global__ __launch_bounds__(256)
void fc_kernel(const float* __restrict__ h, const float* __restrict__ w,
               const float* __restrict__ bfc, float* __restrict__ out) {
  int b = blockIdx.x; int tid = threadIdx.x;
  float s = h[(size_t)b * 512 + tid] * w[tid] + h[(size_t)b * 512 + tid + 256] * w[tid + 256];
  for (int o = 32; o; o >>= 1) s += __shfl_xor(s, o);
  __shared__ float ws4[4];
  if ((tid & 63) == 0) ws4[tid >> 6] = s;
  __syncthreads();
  if (tid == 0) out[b] = ws4[0] + ws4[1] + ws4[2] + ws4[3] + bfc[0];
}

extern "C" void kernel_launch(void* const* d_in, const int* in_sizes, int n_in,
                              void* d_out, int out_size, void* d_ws, size_t ws_size,
                              hipStream_t stream) {
  const float* x     = (const float*)d_in[0];
  const float* v_ih0 = (const float*)d_in[1];
  const float* g_ih0 = (const float*)d_in[2];
  const float* b_ih0 = (const float*)d_in[3];
  const float* v_hh0 = (const float*)d_in[4];
  const float* g_hh0 = (const float*)d_in[5];
  const float* b_hh0 = (const float*)d_in[6];
  const float* v_ih1 = (const float*)d_in[7];
  const float* g_ih1 = (const float*)d_in[8];
  const float* b_ih1 = (const float*)d_in[9];
  const float* v_hh1 = (const float*)d_in[10];
  const float* g_hh1 = (const float*)d_in[11];
  const float* b_hh1 = (const float*)d_in[12];
  const float* w_fc  = (const float*)d_in[13];
  const float* b_fc  = (const float*)d_in[14];
  float* out = (float*)d_out;

  char* w = (char*)d_ws;
  size_t off = 0;
  auto alloc = [&](size_t bytes) -> char* {
    char* p = w + off; off += (bytes + 255) & ~(size_t)255; return p;
  };
  int*   flags  = (int*)alloc(4096 + 256);   // [2][8][64] wave-flags, then claim[8]
  int*   claim  = flags + 1024;
  float* h1fin  = (float*)alloc((size_t)256 * 512 * 4);
  u16*   h0ring = (u16*)alloc((size_t)8 * BH * 2);
  u16*   h1ring = (u16*)alloc((size_t)4 * BH * 2);
  u16*   xb     = (u16*)alloc((size_t)B_SZ * T_SZ * IN_SZ * 2);
  u16*   wih0   = (u16*)alloc((size_t)G3 * IN_SZ * 2);
  u16*   whh0   = (u16*)alloc((size_t)G3 * H_SZ * 2);
  u16*   wih1   = (u16*)alloc((size_t)G3 * H_SZ * 2);
  u16*   whh1   = (u16*)alloc((size_t)G3 * H_SZ * 2);
  if (off > ws_size) return;  // ~18MB; evidenced ws is far larger

  hipMemsetAsync(flags, 0, 4096 + 256, stream);
  norm_cast_kernel<<<384, 256, 0, stream>>>(v_ih0, g_ih0, wih0, IN_SZ);
  norm_cast_kernel<<<384, 256, 0, stream>>>(v_hh0, g_hh0, whh0, H_SZ);
  norm_cast_kernel<<<384, 256, 0, stream>>>(v_ih1, g_ih1, wih1, H_SZ);
  norm_cast_kernel<<<384, 256, 0, stream>>>(v_hh1, g_hh1, whh1, H_SZ);
  castx_kernel<<<4096, 256, 0, stream>>>(x, xb);

  fused_rnn_kernel<<<256, 256, 0, stream>>>(whh0, wih0, b_ih0, b_hh0,
                                            whh1, wih1, b_ih1, b_hh1,
                                            xb, h0ring, h1ring, h1fin,
                                            flags, claim);
  fc_kernel<<<256, 256, 0, stream>>>(h1fin, w_fc, b_fc, out);
}

// Round 11
// 1435.374 us; speedup vs baseline: 8.9798x; 2.6056x over previous
//
#include <hip/hip_runtime.h>
#include <hip/hip_bf16.h>
#include <cstdint>
#include <cstddef>

typedef unsigned short u16;
typedef __attribute__((ext_vector_type(4))) float f32x4;
typedef __attribute__((ext_vector_type(8))) short short8;

#define B_SZ 256
#define T_SZ 256
#define IN_SZ 64
#define H_SZ 512
#define G3 1536
#define BHE (256 * 512)   // elements per ring slot

__device__ __forceinline__ u16 f2bf(float f) {
  union { float f; unsigned int i; } v; v.f = f;
  unsigned int x = v.i;
  unsigned int r = (x + 0x7fffu + ((x >> 16) & 1u)) >> 16;  // RNE
  return (u16)r;
}
__device__ __forceinline__ float sigmoidf_(float x) { return 1.0f / (1.0f + __expf(-x)); }
__device__ __forceinline__ float tanhf_(float x) {
  float e = __expf(-2.0f * x); return (1.0f - e) / (1.0f + e);
}

// ---------------- weight-norm + bf16 cast: one wave per row ----------------
__global__ __launch_bounds__(256)
void norm_cast_kernel(const float* __restrict__ v, const float* __restrict__ g,
                      u16* __restrict__ out, int cols) {
  int row = blockIdx.x * 4 + (threadIdx.x >> 6);
  int lane = threadIdx.x & 63;
  const float* vr = v + (size_t)row * cols;
  float s = 0.f;
  for (int c = lane; c < cols; c += 64) { float t = vr[c]; s += t * t; }
  for (int o = 32; o; o >>= 1) s += __shfl_xor(s, o);
  float scale = g[row] / sqrtf(s);
  for (int c = lane; c < cols; c += 64) out[(size_t)row * cols + c] = f2bf(vr[c] * scale);
}

__global__ __launch_bounds__(256)
void castx_kernel(const float* __restrict__ x, u16* __restrict__ xb) {
  int i = blockIdx.x * 256 + threadIdx.x;
  float4 v = ((const float4*)x)[i];
  ushort4 o;
  o.x = f2bf(v.x); o.y = f2bf(v.y); o.z = f2bf(v.z); o.w = f2bf(v.w);
  ((ushort4*)xb)[i] = o;
}

// ------------- fused 2-layer GRU: both layers in one block, 1 flag/step -----
// 256 blocks x 256 thr (4 waves, 1/SIMD), 1 blk/CU (LDS 96KB). Claim on own
// XCD: g = xcd*2 + (r&1) (16 groups of 16 batch rows), s = r>>1 (16 slices of
// 32 units). Waves: wv&1 = unit-tile (16 units), wv>>1 = layer role.
// Step t: L0 waves compute h0(t) from h0(t-1); L1 waves compute h1(t-1) from
// h0(t-1), h1(t-2) -- ALL inputs from rendezvous t-1 => ONE flag per block per
// step, wave0-only poll (R4/R5-proven sc1 atomics), others parked in barrier.
// Depth-4 rings; WAR implied by the main rendezvous (writer at t+4 has seen
// all peers finish t+3). One buffer_inv per step.
__global__ __launch_bounds__(256, 1)
void fused_rnn_kernel(const u16* __restrict__ whh0c, const u16* __restrict__ wih0c,
                      const u16* __restrict__ whh1c, const u16* __restrict__ wih1c,
                      const float* __restrict__ bih0, const float* __restrict__ bhh0,
                      const float* __restrict__ bih1, const float* __restrict__ bhh1,
                      const u16* __restrict__ xb, u16* __restrict__ h0ring,
                      u16* __restrict__ h1ring, float* __restrict__ h1fin,
                      int* __restrict__ flags, int* __restrict__ claim) {
  __shared__ u16 Wx1[96 * 512];   // Wih1 slice (3x32 gate rows x 512), swizzled
  __shared__ int role_sh;

  const int tid = threadIdx.x;
  if (tid == 0) {
    int xcd;
    asm volatile("s_getreg_b32 %0, hwreg(HW_REG_XCC_ID)" : "=s"(xcd));
    xcd &= 7;
    role_sh = xcd * 64 + atomicAdd(&claim[xcd], 1);
  }
  __syncthreads();
  const int r = role_sh & 63;
  if (r >= 32) return;               // can't happen (pigeonhole 32/XCD)
  const int g = (role_sh >> 6) * 2 + (r & 1);   // batch group (16 rows)
  const int s = r >> 1;              // hidden slice (32 units)

  const int lane = tid & 63;
  const int wv = tid >> 6;
  const int u16i = wv & 1;           // unit-tile within slice
  const int isL1 = wv >> 1;          // layer role
  const int l15 = lane & 15;
  const int q = lane >> 4;
  const int ul = u16i * 16 + l15;    // local unit 0..31
  const int gu = s * 32 + ul;        // global unit
  const int swz = (ul & 7) << 4;
  const size_t arow = (size_t)(g * 16 + l15) * 512;   // A-row base in rings

  // stage Wih1 slice swizzled into LDS (R5-proven pattern)
  for (int idx = tid; idx < 6144; idx += 256) {
    int rr = idx >> 6, c16 = idx & 63;
    int grow = (rr >> 5) * 512 + s * 32 + (rr & 31);
    int sb = (c16 << 4) ^ ((rr & 7) << 4);
    uint4 vv = *(const uint4*)((const char*)wih1c + (size_t)grow * 1024 + sb);
    *(uint4*)((char*)Wx1 + rr * 1024 + (c16 << 4)) = vv;
  }

  // Whh fragments -> registers (48 x short8), per layer role
  const u16* whhp = isL1 ? whh1c : whh0c;
  short8 whf[3][16];
  #pragma unroll
  for (int g3 = 0; g3 < 3; ++g3)
    #pragma unroll
    for (int kk = 0; kk < 16; ++kk)
      whf[g3][kk] = *(const short8*)(whhp + (size_t)(g3 * 512 + gu) * 512 + kk * 32 + q * 8);
  // L0: Wih0 fragments
  short8 wxf[3][2];
  if (!isL1) {
    #pragma unroll
    for (int g3 = 0; g3 < 3; ++g3)
      #pragma unroll
      for (int k2 = 0; k2 < 2; ++k2)
        wxf[g3][k2] = *(const short8*)(wih0c + (size_t)(g3 * 512 + gu) * 64 + k2 * 32 + q * 8);
  }
  const float* bi = isL1 ? bih1 : bih0;
  const float* bh = isL1 ? bhh1 : bhh0;
  const float bi_r = bi[gu], bi_z = bi[512 + gu], bi_n = bi[1024 + gu];
  const float bh_r = bh[gu], bh_z = bh[512 + gu], bh_n = bh[1024 + gu];

  __syncthreads();   // staging visible

  int* gf = flags + g * 64;          // this group's 16 flags (one 64B line)
  float h_old[4] = {0.f, 0.f, 0.f, 0.f};

  for (int t = 0; t <= T_SZ; ++t) {
    if (t > 0) {
      __syncthreads();               // all 4 waves' step t-1 publishes drained
      if (wv == 0) {
        if (lane == 0)
          __hip_atomic_store(&gf[s], t, __ATOMIC_RELAXED, __HIP_MEMORY_SCOPE_AGENT);
        int* p = gf + l15;           // 64 lanes poll 16 flags (4x dup)
        int cap = 0;
        while (__hip_atomic_load(p, __ATOMIC_RELAXED, __HIP_MEMORY_SCOPE_AGENT) < t) {
          __builtin_amdgcn_s_sleep(2);
          if (++cap > 200000) break; // hang breaker; never hit in normal runs
        }
        __builtin_amdgcn_sched_barrier(0);
      }
      __syncthreads();               // release all waves
      asm volatile("buffer_inv sc0" ::: "memory");   // once per step
    }
    if (!isL1) {
      if (t < T_SZ) {
        f32x4 accr = {0.f,0.f,0.f,0.f}, accz = {0.f,0.f,0.f,0.f};
        f32x4 axn  = {0.f,0.f,0.f,0.f}, ahn  = {0.f,0.f,0.f,0.f};
        const u16* xp = xb + ((size_t)(g * 16 + l15) * T_SZ + t) * 64;
        short8 ax0 = *(const short8*)(xp + q * 8);
        short8 ax1 = *(const short8*)(xp + 32 + q * 8);
        accr = __builtin_amdgcn_mfma_f32_16x16x32_bf16(ax0, wxf[0][0], accr, 0, 0, 0);
        accz = __builtin_amdgcn_mfma_f32_16x16x32_bf16(ax0, wxf[1][0], accz, 0, 0, 0);
        axn  = __builtin_amdgcn_mfma_f32_16x16x32_bf16(ax0, wxf[2][0], axn, 0, 0, 0);
        accr = __builtin_amdgcn_mfma_f32_16x16x32_bf16(ax1, wxf[0][1], accr, 0, 0, 0);
        accz = __builtin_amdgcn_mfma_f32_16x16x32_bf16(ax1, wxf[1][1], accz, 0, 0, 0);
        axn  = __builtin_amdgcn_mfma_f32_16x16x32_bf16(ax1, wxf[2][1], axn, 0, 0, 0);
        if (t > 0) {
          const u16* hp = h0ring + (size_t)((t - 1) & 3) * BHE + arow;
          #pragma unroll
          for (int kk = 0; kk < 16; ++kk) {
            short8 a = *(const short8*)(hp + kk * 32 + q * 8);
            accr = __builtin_amdgcn_mfma_f32_16x16x32_bf16(a, whf[0][kk], accr, 0, 0, 0);
            accz = __builtin_amdgcn_mfma_f32_16x16x32_bf16(a, whf[1][kk], accz, 0, 0, 0);
            ahn  = __builtin_amdgcn_mfma_f32_16x16x32_bf16(a, whf[2][kk], ahn, 0, 0, 0);
          }
        }
        u16* dst = h0ring + (size_t)(t & 3) * BHE;
        #pragma unroll
        for (int r2 = 0; r2 < 4; ++r2) {
          float rr = sigmoidf_(accr[r2] + bi_r + bh_r);
          float zz = sigmoidf_(accz[r2] + bi_z + bh_z);
          float nn = tanhf_(axn[r2] + bi_n + rr * (ahn[r2] + bh_n));
          float hv = (1.0f - zz) * nn + zz * h_old[r2];
          h_old[r2] = hv;
          dst[(size_t)(g * 16 + q * 4 + r2) * 512 + gu] = f2bf(hv);
        }
      }
    } else {
      if (t >= 1) {
        f32x4 accr = {0.f,0.f,0.f,0.f}, accz = {0.f,0.f,0.f,0.f};
        f32x4 axn  = {0.f,0.f,0.f,0.f}, ahn  = {0.f,0.f,0.f,0.f};
        {  // gx1 = Wih1 . h0(t-1)   (B from LDS)
          const u16* hp0 = h0ring + (size_t)((t - 1) & 3) * BHE + arow;
          #pragma unroll
          for (int kk = 0; kk < 16; ++kk) {
            short8 a0 = *(const short8*)(hp0 + kk * 32 + q * 8);
            int bofs = (kk * 64 + q * 16) ^ swz;
            short8 br = *(const short8*)((const char*)Wx1 + (size_t)ul * 1024 + bofs);
            short8 bz = *(const short8*)((const char*)Wx1 + (size_t)(32 + ul) * 1024 + bofs);
            short8 bn = *(const short8*)((const char*)Wx1 + (size_t)(64 + ul) * 1024 + bofs);
            accr = __builtin_amdgcn_mfma_f32_16x16x32_bf16(a0, br, accr, 0, 0, 0);
            accz = __builtin_amdgcn_mfma_f32_16x16x32_bf16(a0, bz, accz, 0, 0, 0);
            axn  = __builtin_amdgcn_mfma_f32_16x16x32_bf16(a0, bn, axn, 0, 0, 0);
          }
        }
        if (t >= 2) {  // gh1 = Whh1 . h1(t-2)  (B from registers)
          const u16* hp1 = h1ring + (size_t)((t - 2) & 3) * BHE + arow;
          #pragma unroll
          for (int kk = 0; kk < 16; ++kk) {
            short8 a1 = *(const short8*)(hp1 + kk * 32 + q * 8);
            accr = __builtin_amdgcn_mfma_f32_16x16x32_bf16(a1, whf[0][kk], accr, 0, 0, 0);
            accz = __builtin_amdgcn_mfma_f32_16x16x32_bf16(a1, whf[1][kk], accz, 0, 0, 0);
            ahn  = __builtin_amdgcn_mfma_f32_16x16x32_bf16(a1, whf[2][kk], ahn, 0, 0, 0);
          }
        }
        u16* dst = h1ring + (size_t)((t - 1) & 3) * BHE;
        #pragma unroll
        for (int r2 = 0; r2 < 4; ++r2) {
          float rr = sigmoidf_(accr[r2] + bi_r + bh_r);
          float zz = sigmoidf_(accz[r2] + bi_z + bh_z);
          float nn = tanhf_(axn[r2] + bi_n + rr * (ahn[r2] + bh_n));
          float hv = (1.0f - zz) * nn + zz * h_old[r2];
          h_old[r2] = hv;
          int row = g * 16 + q * 4 + r2;
          if (t < T_SZ) dst[(size_t)row * 512 + gu] = f2bf(hv);
          else          h1fin[(size_t)row * 512 + gu] = hv;   // h1(255)
        }
      }
    }
    asm volatile("s_waitcnt vmcnt(0)" ::: "memory");  // publishes drained to L2
  }
}

// ---------------- final FC: out[b] = h1[b,:] . w_fc + b_fc ------------------
__global__ __launch_bounds__(256)
void fc_kernel(const float* __restrict__ h, const float* __restrict__ w,
               const float* __restrict__ bfc, float* __restrict__ out) {
  int b = blockIdx.x; int tid = threadIdx.x;
  float s = h[(size_t)b * 512 + tid] * w[tid] + h[(size_t)b * 512 + tid + 256] * w[tid + 256];
  for (int o = 32; o; o >>= 1) s += __shfl_xor(s, o);
  __shared__ float ws4[4];
  if ((tid & 63) == 0) ws4[tid >> 6] = s;
  __syncthreads();
  if (tid == 0) out[b] = ws4[0] + ws4[1] + ws4[2] + ws4[3] + bfc[0];
}

extern "C" void kernel_launch(void* const* d_in, const int* in_sizes, int n_in,
                              void* d_out, int out_size, void* d_ws, size_t ws_size,
                              hipStream_t stream) {
  const float* x     = (const float*)d_in[0];
  const float* v_ih0 = (const float*)d_in[1];
  const float* g_ih0 = (const float*)d_in[2];
  const float* b_ih0 = (const float*)d_in[3];
  const float* v_hh0 = (const float*)d_in[4];
  const float* g_hh0 = (const float*)d_in[5];
  const float* b_hh0 = (const float*)d_in[6];
  const float* v_ih1 = (const float*)d_in[7];
  const float* g_ih1 = (const float*)d_in[8];
  const float* b_ih1 = (const float*)d_in[9];
  const float* v_hh1 = (const float*)d_in[10];
  const float* g_hh1 = (const float*)d_in[11];
  const float* b_hh1 = (const float*)d_in[12];
  const float* w_fc  = (const float*)d_in[13];
  const float* b_fc  = (const float*)d_in[14];
  float* out = (float*)d_out;

  char* w = (char*)d_ws;
  size_t off = 0;
  auto alloc = [&](size_t bytes) -> char* {
    char* p = w + off; off += (bytes + 255) & ~(size_t)255; return p;
  };
  int*   flags  = (int*)alloc(4096 + 256);   // 16 groups x 64-int stride, claim[8]
  int*   claim  = flags + 1024;
  float* h1fin  = (float*)alloc((size_t)256 * 512 * 4);
  u16*   h0ring = (u16*)alloc((size_t)4 * BHE * 2);
  u16*   h1ring = (u16*)alloc((size_t)4 * BHE * 2);
  u16*   xb     = (u16*)alloc((size_t)B_SZ * T_SZ * IN_SZ * 2);
  u16*   wih0   = (u16*)alloc((size_t)G3 * IN_SZ * 2);
  u16*   whh0   = (u16*)alloc((size_t)G3 * H_SZ * 2);
  u16*   wih1   = (u16*)alloc((size_t)G3 * H_SZ * 2);
  u16*   whh1   = (u16*)alloc((size_t)G3 * H_SZ * 2);
  if (off > ws_size) return;  // ~14MB; evidenced ws is far larger

  hipMemsetAsync(flags, 0, 4096 + 256, stream);
  norm_cast_kernel<<<384, 256, 0, stream>>>(v_ih0, g_ih0, wih0, IN_SZ);
  norm_cast_kernel<<<384, 256, 0, stream>>>(v_hh0, g_hh0, whh0, H_SZ);
  norm_cast_kernel<<<384, 256, 0, stream>>>(v_ih1, g_ih1, wih1, H_SZ);
  norm_cast_kernel<<<384, 256, 0, stream>>>(v_hh1, g_hh1, whh1, H_SZ);
  castx_kernel<<<4096, 256, 0, stream>>>(x, xb);

  fused_rnn_kernel<<<256, 256, 0, stream>>>(whh0, wih0, whh1, wih1,
                                            b_ih0, b_hh0, b_ih1, b_hh1,
                                            xb, h0ring, h1ring, h1fin,
                                            flags, claim);
  fc_kernel<<<256, 256, 0, stream>>>(h1fin, w_fc, b_fc, out);
}